// Round 15
// baseline (405.374 us; speedup 1.0000x reference)
//
#include <hip/hip_runtime.h>
#include <hip/hip_bf16.h>
#include <cfloat>

// Problem: L=3, B=2, S=2048, D=256, H=8, DK=32, F=1024
#define Lc 3
#define Bc 2
#define Sc 2048
#define Dc 256
#define Hc 8
#define DKc 32
#define Fc 1024

typedef __hip_bfloat16 bf16;
typedef short s8v __attribute__((ext_vector_type(8)));
typedef float f4v __attribute__((ext_vector_type(4)));

// 1/sqrt(32) * log2(e): folded into Q at the QKV-GEMM epilogue so flash can
// use exp2 directly with no per-element scale.
#define QSCALE 0.25504526036067815f

__device__ __forceinline__ float load_f(const void* p, size_t i, int isbf)
{
    return isbf ? __bfloat162float(((const bf16*)p)[i]) : ((const float*)p)[i];
}

// async global->LDS, 16B per lane; LDS dest = wave-uniform base + lane*16.
typedef const __attribute__((address_space(1))) char gchar_t;
typedef __attribute__((address_space(3))) char lchar_t;
__device__ __forceinline__ void glds16(const void* g, void* l)
{
    __builtin_amdgcn_global_load_lds((gchar_t*)(size_t)g, (lchar_t*)(size_t)l,
                                     16, 0, 0);
}

// ---------------------------------------------------------------------------
// Fused prologue (unchanged from round 13). Weights written TRANSPOSED
// (BT layout [N][K], K-contiguous) for global_load_lds staging in the GEMM.
// ---------------------------------------------------------------------------
#define NBLK_REPACK 2304
#define NBLK_CONV   6942
#define NBLK_PACK   1024
#define NBLK_PE     4096

__global__ __launch_bounds__(256) void prologue_fused(
    const void* __restrict__ x, const void* __restrict__ mask,
    const void* __restrict__ pe,
    const void* Wq, const void* Wk, const void* Wv,
    const void* Wo, const void* W1, const void* W2,
    const void* bo, const void* b1, const void* b2,
    const void* g1, const void* be1, const void* g2, const void* be2,
    bf16* __restrict__ wqkv, bf16* __restrict__ dstb, float* __restrict__ pc,
    unsigned* __restrict__ pmask, float* __restrict__ xf,
    bf16* __restrict__ xb, int* __restrict__ flags)
{
    __shared__ int sf[2];
    int tid = threadIdx.x;
    if (tid < 64) {
        const unsigned short* u16 = (const unsigned short*)x;
        int cnt = 0;
        for (int i = tid; i < 256; i += 64) {
            unsigned e = (u16[2 * i] >> 7) & 0xFF;
            cnt += (e >= 90 && e <= 140) ? 1 : 0;
        }
        #pragma unroll
        for (int d = 1; d < 64; d <<= 1) cnt += __shfl_xor(cnt, d);
        const unsigned* mu = (const unsigned*)mask;
        int c2 = ((mu[tid] & 0xFFFFFF00u) == 0) ? 1 : 0;
        #pragma unroll
        for (int d = 1; d < 64; d <<= 1) c2 += __shfl_xor(c2, d);
        if (tid == 0) {
            sf[0] = (cnt >= 128) ? 1 : 0;
            sf[1] = (c2 >= 48) ? 1 : 0;
            if (blockIdx.x == 0) { flags[0] = sf[0]; flags[1] = sf[1]; }
        }
    }
    __syncthreads();
    int isbf = sf[0], mf = sf[1];
    int blk = blockIdx.x;

    if (blk < NBLK_REPACK) {
        int idx = blk * 256 + tid;
        int l   = idx / (3 * Dc * Dc);
        int rem = idx % (3 * Dc * Dc);
        int col = rem / Dc;          // 0..767
        int d   = rem % Dc;
        int mat = col / Dc;
        int hk  = col % Dc;
        int h = hk / DKc, kk = hk % DKc;
        const void* W = (mat == 0) ? Wq : (mat == 1) ? Wk : Wv;
        float v = load_f(W, (size_t)l * (Hc * Dc * DKc) + h * (Dc * DKc) + d * DKc + kk, isbf);
        wqkv[idx] = __float2bfloat16(v);
    } else if (blk < NBLK_REPACK + NBLK_CONV) {
        const int NB0 = Lc * Dc * Dc;            // 196608
        const int NB1 = NB0 + Lc * Dc * Fc;      // 983040
        const int NB2 = NB1 + Lc * Fc * Dc;      // 1769472
        int idx = (blk - NBLK_REPACK) * 256 + tid;
        if (idx < NB2) {
            const void* src; int off;
            if (idx < NB0) {
                int l = idx / (Dc * Dc); int rem = idx % (Dc * Dc);
                int n = rem / Dc, k = rem % Dc;
                src = Wo; off = l * Dc * Dc + k * Dc + n;
            } else if (idx < NB1) {
                int j = idx - NB0;
                int l = j / (Fc * Dc); int rem = j % (Fc * Dc);
                int n = rem / Dc, k = rem % Dc;
                src = W1; off = l * Dc * Fc + k * Fc + n;
            } else {
                int j = idx - NB1;
                int l = j / (Dc * Fc); int rem = j % (Dc * Fc);
                int n = rem / Fc, k = rem % Fc;
                src = W2; off = l * Fc * Dc + k * Dc + n;
            }
            dstb[idx] = __float2bfloat16(load_f(src, off, isbf));
        } else {
            int off = idx - NB2;
            if (off < 7680) {
                const void* src; int lo;
                if (off < 768)       { src = bo;  lo = off; }
                else if (off < 3840) { src = b1;  lo = off - 768; }
                else if (off < 4608) { src = b2;  lo = off - 3840; }
                else if (off < 5376) { src = g1;  lo = off - 4608; }
                else if (off < 6144) { src = be1; lo = off - 5376; }
                else if (off < 6912) { src = g2;  lo = off - 6144; }
                else                 { src = be2; lo = off - 6912; }
                pc[off] = load_f(src, lo, isbf);
            }
        }
    } else if (blk < NBLK_REPACK + NBLK_CONV + NBLK_PACK) {
        int idx = (blk - NBLK_REPACK - NBLK_CONV) * 256 + tid;  // < B*S*S/32
        unsigned wb = 0;
        if (mf) {
            const int* mp = (const int*)mask + (size_t)idx * 32;
            #pragma unroll
            for (int u = 0; u < 8; ++u) {
                uint4 q = *(const uint4*)(mp + u * 4);
                wb |= (q.x ? 1u : 0u) << (u * 4);
                wb |= (q.y ? 1u : 0u) << (u * 4 + 1);
                wb |= (q.z ? 1u : 0u) << (u * 4 + 2);
                wb |= (q.w ? 1u : 0u) << (u * 4 + 3);
            }
        } else {
            const unsigned char* mp = (const unsigned char*)mask + (size_t)idx * 32;
            uint4 a = *(const uint4*)mp;
            uint4 bq = *(const uint4*)(mp + 16);
            const unsigned char* ab = (const unsigned char*)&a;
            const unsigned char* bb = (const unsigned char*)&bq;
            #pragma unroll
            for (int j = 0; j < 16; ++j) {
                wb |= (ab[j] ? 1u : 0u) << j;
                wb |= (bb[j] ? 1u : 0u) << (16 + j);
            }
        }
        pmask[idx] = wb;
    } else {
        int idx = (blk - NBLK_REPACK - NBLK_CONV - NBLK_PACK) * 256 + tid;
        int rem = idx % (Sc * Dc);
        float v = load_f(x, idx, isbf) + load_f(pe, rem, isbf);
        xf[idx] = v;
        xb[idx] = __float2bfloat16(v);
    }
}

// ---------------------------------------------------------------------------
// MFMA GEMM v2 (unchanged): 64x64 tile, BT weights + global_load_lds with
// XOR-swizzled 16B slots. Used for QKV (N=768) and FFN1 (N=1024).
// ---------------------------------------------------------------------------
__global__ __launch_bounds__(256) void gemm_mfma(
    const bf16* __restrict__ A, const bf16* __restrict__ BT,
    const float* __restrict__ bias, void* __restrict__ C,
    int M, int N, int K, int relu, int obf, float ascale, int scale_ncols)
{
    __shared__ __align__(16) short As[4096];
    __shared__ __align__(16) short Bs[4096];
    int tid = threadIdx.x;
    int w = tid >> 6, lane = tid & 63;
    int quad = lane >> 4, l15 = lane & 15;
    int wm0 = (w & 1) * 32, wn0 = (w >> 1) * 32;
    int row0 = blockIdx.y * 64, col0 = blockIdx.x * 64;

    int s0 = w * 128 + lane;
    int s1 = s0 + 64;
    int r0 = s0 >> 3, c0 = ((s0 & 7) ^ (r0 & 7)) * 8;
    int r1 = s1 >> 3, c1 = ((s1 & 7) ^ (r1 & 7)) * 8;
    const bf16* Ag0 = A + (size_t)(row0 + r0) * K + c0;
    const bf16* Ag1 = A + (size_t)(row0 + r1) * K + c1;
    const bf16* Bg0 = BT + (size_t)(col0 + r0) * K + c0;
    const bf16* Bg1 = BT + (size_t)(col0 + r1) * K + c1;
    short* Ad0 = As + w * 1024;
    short* Ad1 = As + w * 1024 + 512;
    short* Bd0 = Bs + w * 1024;
    short* Bd1 = Bs + w * 1024 + 512;

    f4v acc00 = {0.f,0.f,0.f,0.f}, acc01 = acc00, acc10 = acc00, acc11 = acc00;

    int m0 = wm0 + l15, m1 = wm0 + 16 + l15;
    int n0 = wn0 + l15, n1 = wn0 + 16 + l15;
    int sw7 = l15 & 7;

    for (int k0 = 0; k0 < K; k0 += 64) {
        glds16(Ag0 + k0, Ad0);
        glds16(Ag1 + k0, Ad1);
        glds16(Bg0 + k0, Bd0);
        glds16(Bg1 + k0, Bd1);
        __syncthreads();
        #pragma unroll
        for (int kc = 0; kc < 2; ++kc) {
            int sw = ((kc * 4 + quad) ^ sw7) * 8;
            s8v a0 = *(const s8v*)(As + m0 * 64 + sw);
            s8v a1 = *(const s8v*)(As + m1 * 64 + sw);
            s8v b0 = *(const s8v*)(Bs + n0 * 64 + sw);
            s8v b1 = *(const s8v*)(Bs + n1 * 64 + sw);
            acc00 = __builtin_amdgcn_mfma_f32_16x16x32_bf16(a0, b0, acc00, 0, 0, 0);
            acc01 = __builtin_amdgcn_mfma_f32_16x16x32_bf16(a0, b1, acc01, 0, 0, 0);
            acc10 = __builtin_amdgcn_mfma_f32_16x16x32_bf16(a1, b0, acc10, 0, 0, 0);
            acc11 = __builtin_amdgcn_mfma_f32_16x16x32_bf16(a1, b1, acc11, 0, 0, 0);
        }
        __syncthreads();
    }

    float bv0 = bias ? bias[col0 + wn0 + l15] : 0.f;
    float bv1 = bias ? bias[col0 + wn0 + 16 + l15] : 0.f;
    f4v accs[2][2] = {{acc00, acc01}, {acc10, acc11}};
    #pragma unroll
    for (int mt = 0; mt < 2; ++mt) {
        #pragma unroll
        for (int nt = 0; nt < 2; ++nt) {
            int gr = row0 + wm0 + mt * 16 + quad * 4;
            int gc = col0 + wn0 + nt * 16 + l15;
            float badd = nt ? bv1 : bv0;
            float sc = (gc < scale_ncols) ? ascale : 1.f;
            #pragma unroll
            for (int reg = 0; reg < 4; ++reg) {
                float v = accs[mt][nt][reg] * sc + badd;
                if (relu) v = fmaxf(v, 0.f);
                if (obf) ((bf16*)C)[(size_t)(gr + reg) * N + gc] = __float2bfloat16(v);
                else     ((float*)C)[(size_t)(gr + reg) * N + gc] = v;
            }
        }
    }
}

// ---------------------------------------------------------------------------
// MFMA GEMM v3: 32x64 tile for the N=256 GEMMs (Wo, FFN2). Grid M/32 x N/64
// = 512 blocks = 2 blocks/CU (the 64-row tile gave only 1/CU -> exposed
// K-loop latency). 4 waves 2x2 of 16m x 32n; A = 1 glds, B = 2 glds.
// ---------------------------------------------------------------------------
__global__ __launch_bounds__(256) void gemm_mfma32(
    const bf16* __restrict__ A, const bf16* __restrict__ BT,
    const float* __restrict__ bias, void* __restrict__ C,
    int M, int N, int K, int relu, int obf)
{
    __shared__ __align__(16) short As[2048];
    __shared__ __align__(16) short Bs[4096];
    int tid = threadIdx.x;
    int w = tid >> 6, lane = tid & 63;
    int quad = lane >> 4, l15 = lane & 15;
    int wm0 = (w & 1) * 16, wn0 = (w >> 1) * 32;
    int row0 = blockIdx.y * 32, col0 = blockIdx.x * 64;

    int sa = w * 64 + lane;                    // A slot 0..255
    int ra = sa >> 3, ca = ((sa & 7) ^ (ra & 7)) * 8;
    int s0 = w * 128 + lane, s1 = s0 + 64;     // B slots 0..511
    int r0 = s0 >> 3, c0 = ((s0 & 7) ^ (r0 & 7)) * 8;
    int r1 = s1 >> 3, c1 = ((s1 & 7) ^ (r1 & 7)) * 8;
    const bf16* Ag  = A + (size_t)(row0 + ra) * K + ca;
    const bf16* Bg0 = BT + (size_t)(col0 + r0) * K + c0;
    const bf16* Bg1 = BT + (size_t)(col0 + r1) * K + c1;
    short* Ad  = As + w * 512;
    short* Bd0 = Bs + w * 1024;
    short* Bd1 = Bs + w * 1024 + 512;

    f4v acc0 = {0.f,0.f,0.f,0.f}, acc1 = acc0;

    int m0 = wm0 + l15;
    int n0 = wn0 + l15, n1 = wn0 + 16 + l15;
    int sw7 = l15 & 7;

    for (int k0 = 0; k0 < K; k0 += 64) {
        glds16(Ag + k0, Ad);
        glds16(Bg0 + k0, Bd0);
        glds16(Bg1 + k0, Bd1);
        __syncthreads();
        #pragma unroll
        for (int kc = 0; kc < 2; ++kc) {
            int sw = ((kc * 4 + quad) ^ sw7) * 8;
            s8v a0 = *(const s8v*)(As + m0 * 64 + sw);
            s8v b0 = *(const s8v*)(Bs + n0 * 64 + sw);
            s8v b1 = *(const s8v*)(Bs + n1 * 64 + sw);
            acc0 = __builtin_amdgcn_mfma_f32_16x16x32_bf16(a0, b0, acc0, 0, 0, 0);
            acc1 = __builtin_amdgcn_mfma_f32_16x16x32_bf16(a0, b1, acc1, 0, 0, 0);
        }
        __syncthreads();
    }

    float bv0 = bias ? bias[col0 + wn0 + l15] : 0.f;
    float bv1 = bias ? bias[col0 + wn0 + 16 + l15] : 0.f;
    f4v accs[2] = {acc0, acc1};
    #pragma unroll
    for (int nt = 0; nt < 2; ++nt) {
        int gr = row0 + wm0 + quad * 4;
        int gc = col0 + wn0 + nt * 16 + l15;
        float badd = nt ? bv1 : bv0;
        #pragma unroll
        for (int reg = 0; reg < 4; ++reg) {
            float v = accs[nt][reg] + badd;
            if (relu) v = fmaxf(v, 0.f);
            if (obf) ((bf16*)C)[(size_t)(gr + reg) * N + gc] = __float2bfloat16(v);
            else     ((float*)C)[(size_t)(gr + reg) * N + gc] = v;
        }
    }
}

// ---------------------------------------------------------------------------
// MFMA flash attention v7: 4-way t-split (as v6) + K-frags loaded DIRECTLY
// from global (contiguous b128 per lane, L2-hot, shared across q0-blocks) —
// no K LDS array, less staging work, LDS 19.4 -> ~10 KB.
// ---------------------------------------------------------------------------
__global__ __launch_bounds__(256, 8) void flash_mfma(
    const bf16* __restrict__ qkv, const unsigned* __restrict__ pmask,
    bf16* __restrict__ op0, bf16* __restrict__ op1,
    bf16* __restrict__ op2, bf16* __restrict__ op3,
    float* __restrict__ spart)
{
    __shared__ __align__(16) short Vt[2336];      // V^T [d][sigma(t)] skewed
    __shared__ __align__(16) short Pw[4][16 * 72];

    int tid = threadIdx.x;
    int w = tid >> 6;
    int lane = tid & 63;
    int quad = lane >> 4, l15 = lane & 15;
    int q0 = blockIdx.x * 64;
    int h = blockIdx.y;
    int z = blockIdx.z;
    int b = z >> 2, rng = z & 3;
    bf16* op = (rng == 0) ? op0 : (rng == 1) ? op1 : (rng == 2) ? op2 : op3;

    s8v qfrag = *(const s8v*)(qkv + (size_t)(b * Sc + q0 + w * 16 + l15) * 768 + h * 32 + quad * 8);

    f4v o0 = {0.f,0.f,0.f,0.f}, o1 = o0;
    float ssum[4] = {0.f, 0.f, 0.f, 0.f};

    int st = tid >> 2, sd = (tid & 3) * 8;
    int sig = ((st & 15) << 2) | (st >> 4);          // sigma(st)
    short* pwv = Pw[w];
    const unsigned* pmrow = pmask + (size_t)b * Sc * (Sc / 32);
    const bf16* kbase = qkv + (size_t)b * Sc * 768 + 256 + h * 32 + quad * 8;

    for (int it = 0; it < 8; ++it) {
        int t0 = rng * (Sc / 4) + it * 64;
        __syncthreads();
        // stage V^T only (K comes straight from global)
        {
            const bf16* vb = qkv + (size_t)(b * Sc + t0 + st) * 768 + 512 + h * 32 + sd;
            uint4 vw = *(const uint4*)vb;
            const unsigned short* vu = (const unsigned short*)&vw;
            #pragma unroll
            for (int j = 0; j < 8; ++j) Vt[(sd + j) * 72 + sig + sd] = (short)vu[j];
        }
        unsigned mw0[4], mw1[4];
        #pragma unroll
        for (int reg = 0; reg < 4; ++reg) {
            int row = q0 + w * 16 + quad * 4 + reg;
            const unsigned* pp = pmrow + (size_t)row * (Sc / 32) + (t0 >> 5);
            mw0[reg] = pp[0];
            mw1[reg] = pp[1];
        }
        // QK^T: B-frag = K[t=l15+16nt][dk=quad*8..] directly from global
        f4v sfr[4];
        #pragma unroll
        for (int nt = 0; nt < 4; ++nt) {
            s8v kf = *(const s8v*)(kbase + (size_t)(t0 + l15 + 16 * nt) * 768);
            f4v zz = {0.f,0.f,0.f,0.f};
            sfr[nt] = __builtin_amdgcn_mfma_f32_16x16x32_bf16(qfrag, kf, zz, 0, 0, 0);
        }
        __syncthreads();   // Vt staged; also orders Pw reuse
        #pragma unroll
        for (int reg = 0; reg < 4; ++reg) {
            unsigned ta = mw0[reg] >> l15;
            unsigned tb = mw1[reg] >> l15;
            float p0 = exp2f(sfr[0][reg]); if (ta & 1u)         p0 = 0.f;
            float p1 = exp2f(sfr[1][reg]); if ((ta >> 16) & 1u) p1 = 0.f;
            float p2 = exp2f(sfr[2][reg]); if (tb & 1u)         p2 = 0.f;
            float p3 = exp2f(sfr[3][reg]); if ((tb >> 16) & 1u) p3 = 0.f;
            ssum[reg] += (p0 + p1) + (p2 + p3);
            bf16 h0 = __float2bfloat16(p0), h1 = __float2bfloat16(p1);
            bf16 h2 = __float2bfloat16(p2), h3 = __float2bfloat16(p3);
            unsigned lo = (unsigned)*(unsigned short*)&h0 | ((unsigned)*(unsigned short*)&h1 << 16);
            unsigned hi = (unsigned)*(unsigned short*)&h2 | ((unsigned)*(unsigned short*)&h3 << 16);
            uint2 pk = {lo, hi};
            *(uint2*)(pwv + (quad * 4 + reg) * 72 + l15 * 4) = pk;
        }
        #pragma unroll
        for (int kc = 0; kc < 2; ++kc) {
            s8v pf  = *(const s8v*)(pwv + l15 * 72 + kc * 32 + quad * 8);
            s8v vf0 = *(const s8v*)(Vt + l15 * 72 + kc * 32 + quad * 8 + (l15 & 24));
            s8v vf1 = *(const s8v*)(Vt + (l15 + 16) * 72 + kc * 32 + quad * 8 + ((l15 + 16) & 24));
            o0 = __builtin_amdgcn_mfma_f32_16x16x32_bf16(pf, vf0, o0, 0, 0, 0);
            o1 = __builtin_amdgcn_mfma_f32_16x16x32_bf16(pf, vf1, o1, 0, 0, 0);
        }
    }

    #pragma unroll
    for (int reg = 0; reg < 4; ++reg) {
        #pragma unroll
        for (int d = 1; d < 16; d <<= 1) ssum[reg] += __shfl_xor(ssum[reg], d);
    }

    #pragma unroll
    for (int reg = 0; reg < 4; ++reg) {
        int row = q0 + w * 16 + quad * 4 + reg;
        size_t ob = (size_t)(b * Sc + row) * Dc + h * DKc;
        op[ob + l15]      = __float2bfloat16(o0[reg]);
        op[ob + 16 + l15] = __float2bfloat16(o1[reg]);
        if (l15 == 0)
            spart[((size_t)(rng * Bc + b) * Hc + h) * Sc + row] = ssum[reg];
    }
}

// attn = sum_r o_r / sum_r s_r   (op2 aliases attn_out: same-idx RAW, safe)
__global__ __launch_bounds__(256) void attn_merge(
    const bf16* __restrict__ op0, const bf16* __restrict__ op1,
    const bf16* __restrict__ op2, const bf16* __restrict__ op3,
    const float* __restrict__ spart, bf16* __restrict__ attn_out)
{
    int idx = blockIdx.x * 256 + threadIdx.x;    // < B*S*D = 1048576
    int d = idx & 255;
    int h = d >> 5;
    int row = (idx >> 8) & (Sc - 1);
    int b = idx >> 19;
    float o = (__bfloat162float(op0[idx]) + __bfloat162float(op1[idx]))
            + (__bfloat162float(op2[idx]) + __bfloat162float(op3[idx]));
    float s = 0.f;
    #pragma unroll
    for (int r = 0; r < 4; ++r)
        s += spart[((size_t)(r * Bc + b) * Hc + h) * Sc + row];
    attn_out[idx] = __float2bfloat16(o / fmaxf(s, 1e-30f));
}

// xf = LN(a + xf)*g + b; xb = bf16(xf); optionally also write final output.
__global__ __launch_bounds__(256) void add_ln(
    const float* __restrict__ a, float* __restrict__ xf, bf16* __restrict__ xb,
    const float* __restrict__ g, const float* __restrict__ b,
    void* __restrict__ dout, const int* __restrict__ flags)
{
    __shared__ float ws4[2][4];
    int row = blockIdx.x, d = threadIdx.x;
    size_t idx = (size_t)row * Dc + d;
    float v = a[idx] + xf[idx];
    float s = v;
    #pragma unroll
    for (int dd = 1; dd < 64; dd <<= 1) s += __shfl_xor(s, dd);
    if ((d & 63) == 0) ws4[0][d >> 6] = s;
    __syncthreads();
    float mu = (ws4[0][0] + ws4[0][1] + ws4[0][2] + ws4[0][3]) * (1.f / Dc);
    float c = v - mu;
    float q = c * c;
    #pragma unroll
    for (int dd = 1; dd < 64; dd <<= 1) q += __shfl_xor(q, dd);
    if ((d & 63) == 0) ws4[1][d >> 6] = q;
    __syncthreads();
    float var = (ws4[1][0] + ws4[1][1] + ws4[1][2] + ws4[1][3]) * (1.f / Dc);
    float r2 = c * rsqrtf(var + 1e-7f) * g[d] + b[d];
    xf[idx] = r2;
    xb[idx] = __float2bfloat16(r2);
    if (dout) {
        if (flags[0]) ((bf16*)dout)[idx] = __float2bfloat16(r2);
        else          ((float*)dout)[idx] = r2;
    }
}

// ---------------------------------------------------------------------------
extern "C" void kernel_launch(void* const* d_in, const int* in_sizes, int n_in,
                              void* d_out, int out_size, void* d_ws, size_t ws_size,
                              hipStream_t stream)
{
    const void* x    = d_in[0];
    const void* mask = d_in[1];
    const void* pe   = d_in[2];
    const void* Wq   = d_in[3];
    const void* Wk   = d_in[4];
    const void* Wv   = d_in[5];
    const void* Wo   = d_in[6];
    const void* bo   = d_in[7];
    const void* ln1g = d_in[8];
    const void* ln1b = d_in[9];
    const void* W1   = d_in[10];
    const void* b1   = d_in[11];
    const void* W2   = d_in[12];
    const void* b2   = d_in[13];
    const void* ln2g = d_in[14];
    const void* ln2b = d_in[15];

    const int M = Bc * Sc;  // 4096
    char* ws = (char*)d_ws;
    const size_t MB = 1024 * 1024;
    int*      flags    = (int*)ws;                        // 256 B
    float*    xf32     = (float*)(ws + 256);              // 4 MiB
    float*    obuf     = (float*)(ws + 256 + 4 * MB);     // 4 MiB (op0/op1)
    char*     bigc     = ws + 256 + 8 * MB;               // 8 MiB (qkv/hbuf/op3)
    bf16*     xbf      = (bf16*)(ws + 256 + 16 * MB);     // 2 MiB
    bf16*     attn_out = (bf16*)(ws + 256 + 18 * MB);     // 2 MiB (op2 alias)
    bf16*     wqkv     = (bf16*)(ws + 256 + 20 * MB);     // weights (BT)
    bf16*     woc      = wqkv + (size_t)Lc * Dc * 3 * Dc;
    bf16*     w1c      = woc + (size_t)Lc * Dc * Dc;
    bf16*     w2c      = w1c + (size_t)Lc * Dc * Fc;
    float*    pc       = (float*)(w2c + (size_t)Lc * Fc * Dc);
    unsigned* pmask    = (unsigned*)(ws + 256 + 25 * MB); // 1 MiB
    float*    spart    = (float*)(ws + 256 + 26 * MB);    // 512 KiB (4 ranges)

    bf16* qkv  = (bf16*)bigc;          // M*768 bf16 = exactly 6 MiB
    bf16* hbuf = (bf16*)bigc;          // M*1024 bf16 = 8 MiB (qkv+op3 dead)
    bf16* op0  = (bf16*)obuf;          // 2 MiB
    bf16* op1  = op0 + (size_t)M * Dc; // 2 MiB
    bf16* op2  = attn_out;             // 2 MiB (merge writes same idx after read)
    bf16* op3  = (bf16*)(bigc + 6 * MB); // 2 MiB tail of bigc (free during flash)

    float* pc_bo   = pc;
    float* pc_b1   = pc + 768;
    float* pc_b2   = pc + 3840;
    float* pc_ln1g = pc + 4608;
    float* pc_ln1b = pc + 5376;
    float* pc_ln2g = pc + 6144;
    float* pc_ln2b = pc + 6912;

    prologue_fused<<<NBLK_REPACK + NBLK_CONV + NBLK_PACK + NBLK_PE, 256, 0, stream>>>(
        x, mask, pe, Wq, Wk, Wv, Wo, W1, W2, bo, b1, b2,
        ln1g, ln1b, ln2g, ln2b, wqkv, woc, pc, pmask, xf32, xbf, flags);

    for (int l = 0; l < Lc; ++l) {
        // QKV: [4096,256] @ BT[768,256] -> bf16; q cols pre-scaled by QSCALE
        gemm_mfma<<<dim3(3 * Dc / 64, M / 64), 256, 0, stream>>>(
            xbf, wqkv + (size_t)l * Dc * 3 * Dc, nullptr, qkv, M, 3 * Dc, Dc, 0, 1,
            QSCALE, Dc);
        flash_mfma<<<dim3(Sc / 64, Hc, Bc * 4), 256, 0, stream>>>(
            qkv, pmask, op0, op1, op2, op3, spart);
        attn_merge<<<(Bc * Sc * Dc) / 256, 256, 0, stream>>>(
            op0, op1, op2, op3, spart, attn_out);
        // Wo: [4096,256] @ BT[256,256] + bo -> f32 (32-row tile, 2 blocks/CU)
        gemm_mfma32<<<dim3(Dc / 64, M / 32), 256, 0, stream>>>(
            attn_out, woc + (size_t)l * Dc * Dc, pc_bo + l * Dc, obuf, M, Dc, Dc, 0, 0);
        add_ln<<<M, 256, 0, stream>>>(obuf, xf32, xbf,
            pc_ln1g + l * Dc, pc_ln1b + l * Dc, nullptr, flags);
        // FFN1: [4096,256] @ BT[1024,256] + b1, relu -> bf16
        gemm_mfma<<<dim3(Fc / 64, M / 64), 256, 0, stream>>>(
            xbf, w1c + (size_t)l * Dc * Fc, pc_b1 + l * Fc, hbuf, M, Fc, Dc, 1, 1,
            1.f, 0);
        // FFN2: [4096,1024] @ BT[256,1024] + b2 -> f32 (32-row tile)
        gemm_mfma32<<<dim3(Dc / 64, M / 32), 256, 0, stream>>>(
            hbuf, w2c + (size_t)l * Fc * Dc, pc_b2 + l * Dc, obuf, M, Dc, Fc, 0, 0);
        // last LN also writes the final output (store_out folded in)
        add_ln<<<M, 256, 0, stream>>>(obuf, xf32, xbf,
            pc_ln2g + l * Dc, pc_ln2b + l * Dc,
            (l == Lc - 1) ? d_out : nullptr, flags);
    }
}

// Round 16
// 383.003 us; speedup vs baseline: 1.0584x; 1.0584x over previous
//
#include <hip/hip_runtime.h>
#include <hip/hip_bf16.h>
#include <cfloat>

// Problem: L=3, B=2, S=2048, D=256, H=8, DK=32, F=1024
#define Lc 3
#define Bc 2
#define Sc 2048
#define Dc 256
#define Hc 8
#define DKc 32
#define Fc 1024

typedef __hip_bfloat16 bf16;
typedef short s8v __attribute__((ext_vector_type(8)));
typedef float f4v __attribute__((ext_vector_type(4)));

// 1/sqrt(32) * log2(e): folded into Q at the QKV-GEMM epilogue so flash can
// use exp2 directly with no per-element scale.
#define QSCALE 0.25504526036067815f

__device__ __forceinline__ float load_f(const void* p, size_t i, int isbf)
{
    return isbf ? __bfloat162float(((const bf16*)p)[i]) : ((const float*)p)[i];
}

// async global->LDS, 16B per lane; LDS dest = wave-uniform base + lane*16.
typedef const __attribute__((address_space(1))) char gchar_t;
typedef __attribute__((address_space(3))) char lchar_t;
__device__ __forceinline__ void glds16(const void* g, void* l)
{
    __builtin_amdgcn_global_load_lds((gchar_t*)(size_t)g, (lchar_t*)(size_t)l,
                                     16, 0, 0);
}

// ---------------------------------------------------------------------------
// Fused prologue (unchanged). Weights written TRANSPOSED (BT layout [N][K]).
// ---------------------------------------------------------------------------
#define NBLK_REPACK 2304
#define NBLK_CONV   6942
#define NBLK_PACK   1024
#define NBLK_PE     4096

__global__ __launch_bounds__(256) void prologue_fused(
    const void* __restrict__ x, const void* __restrict__ mask,
    const void* __restrict__ pe,
    const void* Wq, const void* Wk, const void* Wv,
    const void* Wo, const void* W1, const void* W2,
    const void* bo, const void* b1, const void* b2,
    const void* g1, const void* be1, const void* g2, const void* be2,
    bf16* __restrict__ wqkv, bf16* __restrict__ dstb, float* __restrict__ pc,
    unsigned* __restrict__ pmask, float* __restrict__ xf,
    bf16* __restrict__ xb, int* __restrict__ flags)
{
    __shared__ int sf[2];
    int tid = threadIdx.x;
    if (tid < 64) {
        const unsigned short* u16 = (const unsigned short*)x;
        int cnt = 0;
        for (int i = tid; i < 256; i += 64) {
            unsigned e = (u16[2 * i] >> 7) & 0xFF;
            cnt += (e >= 90 && e <= 140) ? 1 : 0;
        }
        #pragma unroll
        for (int d = 1; d < 64; d <<= 1) cnt += __shfl_xor(cnt, d);
        const unsigned* mu = (const unsigned*)mask;
        int c2 = ((mu[tid] & 0xFFFFFF00u) == 0) ? 1 : 0;
        #pragma unroll
        for (int d = 1; d < 64; d <<= 1) c2 += __shfl_xor(c2, d);
        if (tid == 0) {
            sf[0] = (cnt >= 128) ? 1 : 0;
            sf[1] = (c2 >= 48) ? 1 : 0;
            if (blockIdx.x == 0) { flags[0] = sf[0]; flags[1] = sf[1]; }
        }
    }
    __syncthreads();
    int isbf = sf[0], mf = sf[1];
    int blk = blockIdx.x;

    if (blk < NBLK_REPACK) {
        int idx = blk * 256 + tid;
        int l   = idx / (3 * Dc * Dc);
        int rem = idx % (3 * Dc * Dc);
        int col = rem / Dc;          // 0..767
        int d   = rem % Dc;
        int mat = col / Dc;
        int hk  = col % Dc;
        int h = hk / DKc, kk = hk % DKc;
        const void* W = (mat == 0) ? Wq : (mat == 1) ? Wk : Wv;
        float v = load_f(W, (size_t)l * (Hc * Dc * DKc) + h * (Dc * DKc) + d * DKc + kk, isbf);
        wqkv[idx] = __float2bfloat16(v);
    } else if (blk < NBLK_REPACK + NBLK_CONV) {
        const int NB0 = Lc * Dc * Dc;            // 196608
        const int NB1 = NB0 + Lc * Dc * Fc;      // 983040
        const int NB2 = NB1 + Lc * Fc * Dc;      // 1769472
        int idx = (blk - NBLK_REPACK) * 256 + tid;
        if (idx < NB2) {
            const void* src; int off;
            if (idx < NB0) {
                int l = idx / (Dc * Dc); int rem = idx % (Dc * Dc);
                int n = rem / Dc, k = rem % Dc;
                src = Wo; off = l * Dc * Dc + k * Dc + n;
            } else if (idx < NB1) {
                int j = idx - NB0;
                int l = j / (Fc * Dc); int rem = j % (Fc * Dc);
                int n = rem / Dc, k = rem % Dc;
                src = W1; off = l * Dc * Fc + k * Fc + n;
            } else {
                int j = idx - NB1;
                int l = j / (Dc * Fc); int rem = j % (Dc * Fc);
                int n = rem / Fc, k = rem % Fc;
                src = W2; off = l * Fc * Dc + k * Dc + n;
            }
            dstb[idx] = __float2bfloat16(load_f(src, off, isbf));
        } else {
            int off = idx - NB2;
            if (off < 7680) {
                const void* src; int lo;
                if (off < 768)       { src = bo;  lo = off; }
                else if (off < 3840) { src = b1;  lo = off - 768; }
                else if (off < 4608) { src = b2;  lo = off - 3840; }
                else if (off < 5376) { src = g1;  lo = off - 4608; }
                else if (off < 6144) { src = be1; lo = off - 5376; }
                else if (off < 6912) { src = g2;  lo = off - 6144; }
                else                 { src = be2; lo = off - 6912; }
                pc[off] = load_f(src, lo, isbf);
            }
        }
    } else if (blk < NBLK_REPACK + NBLK_CONV + NBLK_PACK) {
        int idx = (blk - NBLK_REPACK - NBLK_CONV) * 256 + tid;  // < B*S*S/32
        unsigned wb = 0;
        if (mf) {
            const int* mp = (const int*)mask + (size_t)idx * 32;
            #pragma unroll
            for (int u = 0; u < 8; ++u) {
                uint4 q = *(const uint4*)(mp + u * 4);
                wb |= (q.x ? 1u : 0u) << (u * 4);
                wb |= (q.y ? 1u : 0u) << (u * 4 + 1);
                wb |= (q.z ? 1u : 0u) << (u * 4 + 2);
                wb |= (q.w ? 1u : 0u) << (u * 4 + 3);
            }
        } else {
            const unsigned char* mp = (const unsigned char*)mask + (size_t)idx * 32;
            uint4 a = *(const uint4*)mp;
            uint4 bq = *(const uint4*)(mp + 16);
            const unsigned char* ab = (const unsigned char*)&a;
            const unsigned char* bb = (const unsigned char*)&bq;
            #pragma unroll
            for (int j = 0; j < 16; ++j) {
                wb |= (ab[j] ? 1u : 0u) << j;
                wb |= (bb[j] ? 1u : 0u) << (16 + j);
            }
        }
        pmask[idx] = wb;
    } else {
        int idx = (blk - NBLK_REPACK - NBLK_CONV - NBLK_PACK) * 256 + tid;
        int rem = idx % (Sc * Dc);
        float v = load_f(x, idx, isbf) + load_f(pe, rem, isbf);
        xf[idx] = v;
        xb[idx] = __float2bfloat16(v);
    }
}

// ---------------------------------------------------------------------------
// MFMA GEMM v2: 64x64 tile, BT weights + global_load_lds, XOR-swizzled slots.
// Used for QKV (N=768) and FFN1 (N=1024).
// ---------------------------------------------------------------------------
__global__ __launch_bounds__(256) void gemm_mfma(
    const bf16* __restrict__ A, const bf16* __restrict__ BT,
    const float* __restrict__ bias, void* __restrict__ C,
    int M, int N, int K, int relu, int obf, float ascale, int scale_ncols)
{
    __shared__ __align__(16) short As[4096];
    __shared__ __align__(16) short Bs[4096];
    int tid = threadIdx.x;
    int w = tid >> 6, lane = tid & 63;
    int quad = lane >> 4, l15 = lane & 15;
    int wm0 = (w & 1) * 32, wn0 = (w >> 1) * 32;
    int row0 = blockIdx.y * 64, col0 = blockIdx.x * 64;

    int s0 = w * 128 + lane;
    int s1 = s0 + 64;
    int r0 = s0 >> 3, c0 = ((s0 & 7) ^ (r0 & 7)) * 8;
    int r1 = s1 >> 3, c1 = ((s1 & 7) ^ (r1 & 7)) * 8;
    const bf16* Ag0 = A + (size_t)(row0 + r0) * K + c0;
    const bf16* Ag1 = A + (size_t)(row0 + r1) * K + c1;
    const bf16* Bg0 = BT + (size_t)(col0 + r0) * K + c0;
    const bf16* Bg1 = BT + (size_t)(col0 + r1) * K + c1;
    short* Ad0 = As + w * 1024;
    short* Ad1 = As + w * 1024 + 512;
    short* Bd0 = Bs + w * 1024;
    short* Bd1 = Bs + w * 1024 + 512;

    f4v acc00 = {0.f,0.f,0.f,0.f}, acc01 = acc00, acc10 = acc00, acc11 = acc00;

    int m0 = wm0 + l15, m1 = wm0 + 16 + l15;
    int n0 = wn0 + l15, n1 = wn0 + 16 + l15;
    int sw7 = l15 & 7;

    for (int k0 = 0; k0 < K; k0 += 64) {
        glds16(Ag0 + k0, Ad0);
        glds16(Ag1 + k0, Ad1);
        glds16(Bg0 + k0, Bd0);
        glds16(Bg1 + k0, Bd1);
        __syncthreads();
        #pragma unroll
        for (int kc = 0; kc < 2; ++kc) {
            int sw = ((kc * 4 + quad) ^ sw7) * 8;
            s8v a0 = *(const s8v*)(As + m0 * 64 + sw);
            s8v a1 = *(const s8v*)(As + m1 * 64 + sw);
            s8v b0 = *(const s8v*)(Bs + n0 * 64 + sw);
            s8v b1 = *(const s8v*)(Bs + n1 * 64 + sw);
            acc00 = __builtin_amdgcn_mfma_f32_16x16x32_bf16(a0, b0, acc00, 0, 0, 0);
            acc01 = __builtin_amdgcn_mfma_f32_16x16x32_bf16(a0, b1, acc01, 0, 0, 0);
            acc10 = __builtin_amdgcn_mfma_f32_16x16x32_bf16(a1, b0, acc10, 0, 0, 0);
            acc11 = __builtin_amdgcn_mfma_f32_16x16x32_bf16(a1, b1, acc11, 0, 0, 0);
        }
        __syncthreads();
    }

    float bv0 = bias ? bias[col0 + wn0 + l15] : 0.f;
    float bv1 = bias ? bias[col0 + wn0 + 16 + l15] : 0.f;
    f4v accs[2][2] = {{acc00, acc01}, {acc10, acc11}};
    #pragma unroll
    for (int mt = 0; mt < 2; ++mt) {
        #pragma unroll
        for (int nt = 0; nt < 2; ++nt) {
            int gr = row0 + wm0 + mt * 16 + quad * 4;
            int gc = col0 + wn0 + nt * 16 + l15;
            float badd = nt ? bv1 : bv0;
            float sc = (gc < scale_ncols) ? ascale : 1.f;
            #pragma unroll
            for (int reg = 0; reg < 4; ++reg) {
                float v = accs[mt][nt][reg] * sc + badd;
                if (relu) v = fmaxf(v, 0.f);
                if (obf) ((bf16*)C)[(size_t)(gr + reg) * N + gc] = __float2bfloat16(v);
                else     ((float*)C)[(size_t)(gr + reg) * N + gc] = v;
            }
        }
    }
}

// ---------------------------------------------------------------------------
// MFMA GEMM v3: 32x64 tile for the N=256 GEMMs (Wo, FFN2) — kept from r15
// (non-flash time 267 -> 254 µs with this).
// ---------------------------------------------------------------------------
__global__ __launch_bounds__(256) void gemm_mfma32(
    const bf16* __restrict__ A, const bf16* __restrict__ BT,
    const float* __restrict__ bias, void* __restrict__ C,
    int M, int N, int K, int relu, int obf)
{
    __shared__ __align__(16) short As[2048];
    __shared__ __align__(16) short Bs[4096];
    int tid = threadIdx.x;
    int w = tid >> 6, lane = tid & 63;
    int quad = lane >> 4, l15 = lane & 15;
    int wm0 = (w & 1) * 16, wn0 = (w >> 1) * 32;
    int row0 = blockIdx.y * 32, col0 = blockIdx.x * 64;

    int sa = w * 64 + lane;                    // A slot 0..255
    int ra = sa >> 3, ca = ((sa & 7) ^ (ra & 7)) * 8;
    int s0 = w * 128 + lane, s1 = s0 + 64;     // B slots 0..511
    int r0 = s0 >> 3, c0 = ((s0 & 7) ^ (r0 & 7)) * 8;
    int r1 = s1 >> 3, c1 = ((s1 & 7) ^ (r1 & 7)) * 8;
    const bf16* Ag  = A + (size_t)(row0 + ra) * K + ca;
    const bf16* Bg0 = BT + (size_t)(col0 + r0) * K + c0;
    const bf16* Bg1 = BT + (size_t)(col0 + r1) * K + c1;
    short* Ad  = As + w * 512;
    short* Bd0 = Bs + w * 1024;
    short* Bd1 = Bs + w * 1024 + 512;

    f4v acc0 = {0.f,0.f,0.f,0.f}, acc1 = acc0;

    int m0 = wm0 + l15;
    int n0 = wn0 + l15, n1 = wn0 + 16 + l15;
    int sw7 = l15 & 7;

    for (int k0 = 0; k0 < K; k0 += 64) {
        glds16(Ag + k0, Ad);
        glds16(Bg0 + k0, Bd0);
        glds16(Bg1 + k0, Bd1);
        __syncthreads();
        #pragma unroll
        for (int kc = 0; kc < 2; ++kc) {
            int sw = ((kc * 4 + quad) ^ sw7) * 8;
            s8v a0 = *(const s8v*)(As + m0 * 64 + sw);
            s8v b0 = *(const s8v*)(Bs + n0 * 64 + sw);
            s8v b1 = *(const s8v*)(Bs + n1 * 64 + sw);
            acc0 = __builtin_amdgcn_mfma_f32_16x16x32_bf16(a0, b0, acc0, 0, 0, 0);
            acc1 = __builtin_amdgcn_mfma_f32_16x16x32_bf16(a0, b1, acc1, 0, 0, 0);
        }
        __syncthreads();
    }

    float bv0 = bias ? bias[col0 + wn0 + l15] : 0.f;
    float bv1 = bias ? bias[col0 + wn0 + 16 + l15] : 0.f;
    f4v accs[2] = {acc0, acc1};
    #pragma unroll
    for (int nt = 0; nt < 2; ++nt) {
        int gr = row0 + wm0 + quad * 4;
        int gc = col0 + wn0 + nt * 16 + l15;
        float badd = nt ? bv1 : bv0;
        #pragma unroll
        for (int reg = 0; reg < 4; ++reg) {
            float v = accs[nt][reg] + badd;
            if (relu) v = fmaxf(v, 0.f);
            if (obf) ((bf16*)C)[(size_t)(gr + reg) * N + gc] = __float2bfloat16(v);
            else     ((float*)C)[(size_t)(gr + reg) * N + gc] = v;
        }
    }
}

// ---------------------------------------------------------------------------
// MFMA flash attention v6 (REVERTED from v7: K back in LDS — global K-frags
// put ~200cyc L2 loads on the QK^T critical path and the (256,8) bound cut
// VGPR to 32; measured 43.0 -> 50.4 µs regression. This is the r14 body.)
// 4-way t-split; NO-MAX softmax; partials merge by pure addition.
// ---------------------------------------------------------------------------
__global__ __launch_bounds__(256) void flash_mfma(
    const bf16* __restrict__ qkv, const unsigned* __restrict__ pmask,
    bf16* __restrict__ op0, bf16* __restrict__ op1,
    bf16* __restrict__ op2, bf16* __restrict__ op3,
    float* __restrict__ spart)
{
    __shared__ __align__(16) short Ks[64 * 40];   // K [t][dk]
    __shared__ __align__(16) short Vt[2336];      // V^T [d][sigma(t)] skewed
    __shared__ __align__(16) short Pw[4][16 * 72];

    int tid = threadIdx.x;
    int w = tid >> 6;
    int lane = tid & 63;
    int quad = lane >> 4, l15 = lane & 15;
    int q0 = blockIdx.x * 64;
    int h = blockIdx.y;
    int z = blockIdx.z;
    int b = z >> 2, rng = z & 3;
    bf16* op = (rng == 0) ? op0 : (rng == 1) ? op1 : (rng == 2) ? op2 : op3;

    s8v qfrag = *(const s8v*)(qkv + (size_t)(b * Sc + q0 + w * 16 + l15) * 768 + h * 32 + quad * 8);

    f4v o0 = {0.f,0.f,0.f,0.f}, o1 = o0;
    float ssum[4] = {0.f, 0.f, 0.f, 0.f};

    int st = tid >> 2, sd = (tid & 3) * 8;
    int sig = ((st & 15) << 2) | (st >> 4);          // sigma(st)
    short* pwv = Pw[w];
    const unsigned* pmrow = pmask + (size_t)b * Sc * (Sc / 32);

    for (int it = 0; it < 8; ++it) {
        int t0 = rng * (Sc / 4) + it * 64;
        __syncthreads();
        {
            const bf16* kvb = qkv + (size_t)(b * Sc + t0 + st) * 768 + h * 32 + sd;
            uint4 kw = *(const uint4*)(kvb + 256);
            *(uint4*)(Ks + st * 40 + sd) = kw;
            uint4 vw = *(const uint4*)(kvb + 512);
            const unsigned short* vu = (const unsigned short*)&vw;
            #pragma unroll
            for (int j = 0; j < 8; ++j) Vt[(sd + j) * 72 + sig + sd] = (short)vu[j];
        }
        unsigned mw0[4], mw1[4];
        #pragma unroll
        for (int reg = 0; reg < 4; ++reg) {
            int row = q0 + w * 16 + quad * 4 + reg;
            const unsigned* pp = pmrow + (size_t)row * (Sc / 32) + (t0 >> 5);
            mw0[reg] = pp[0];
            mw1[reg] = pp[1];
        }
        __syncthreads();

        f4v sfr[4];
        #pragma unroll
        for (int nt = 0; nt < 4; ++nt) {
            s8v kf = *(const s8v*)(Ks + (l15 + 16 * nt) * 40 + quad * 8);
            f4v zz = {0.f,0.f,0.f,0.f};
            sfr[nt] = __builtin_amdgcn_mfma_f32_16x16x32_bf16(qfrag, kf, zz, 0, 0, 0);
        }
        #pragma unroll
        for (int reg = 0; reg < 4; ++reg) {
            unsigned ta = mw0[reg] >> l15;
            unsigned tb = mw1[reg] >> l15;
            float p0 = exp2f(sfr[0][reg]); if (ta & 1u)         p0 = 0.f;
            float p1 = exp2f(sfr[1][reg]); if ((ta >> 16) & 1u) p1 = 0.f;
            float p2 = exp2f(sfr[2][reg]); if (tb & 1u)         p2 = 0.f;
            float p3 = exp2f(sfr[3][reg]); if ((tb >> 16) & 1u) p3 = 0.f;
            ssum[reg] += (p0 + p1) + (p2 + p3);
            bf16 h0 = __float2bfloat16(p0), h1 = __float2bfloat16(p1);
            bf16 h2 = __float2bfloat16(p2), h3 = __float2bfloat16(p3);
            unsigned lo = (unsigned)*(unsigned short*)&h0 | ((unsigned)*(unsigned short*)&h1 << 16);
            unsigned hi = (unsigned)*(unsigned short*)&h2 | ((unsigned)*(unsigned short*)&h3 << 16);
            uint2 pk = {lo, hi};
            *(uint2*)(pwv + (quad * 4 + reg) * 72 + l15 * 4) = pk;
        }
        #pragma unroll
        for (int kc = 0; kc < 2; ++kc) {
            s8v pf  = *(const s8v*)(pwv + l15 * 72 + kc * 32 + quad * 8);
            s8v vf0 = *(const s8v*)(Vt + l15 * 72 + kc * 32 + quad * 8 + (l15 & 24));
            s8v vf1 = *(const s8v*)(Vt + (l15 + 16) * 72 + kc * 32 + quad * 8 + ((l15 + 16) & 24));
            o0 = __builtin_amdgcn_mfma_f32_16x16x32_bf16(pf, vf0, o0, 0, 0, 0);
            o1 = __builtin_amdgcn_mfma_f32_16x16x32_bf16(pf, vf1, o1, 0, 0, 0);
        }
    }

    #pragma unroll
    for (int reg = 0; reg < 4; ++reg) {
        #pragma unroll
        for (int d = 1; d < 16; d <<= 1) ssum[reg] += __shfl_xor(ssum[reg], d);
    }

    #pragma unroll
    for (int reg = 0; reg < 4; ++reg) {
        int row = q0 + w * 16 + quad * 4 + reg;
        size_t ob = (size_t)(b * Sc + row) * Dc + h * DKc;
        op[ob + l15]      = __float2bfloat16(o0[reg]);
        op[ob + 16 + l15] = __float2bfloat16(o1[reg]);
        if (l15 == 0)
            spart[((size_t)(rng * Bc + b) * Hc + h) * Sc + row] = ssum[reg];
    }
}

// attn = sum_r o_r / sum_r s_r   (op2 aliases attn_out: same-idx RAW, safe)
__global__ __launch_bounds__(256) void attn_merge(
    const bf16* __restrict__ op0, const bf16* __restrict__ op1,
    const bf16* __restrict__ op2, const bf16* __restrict__ op3,
    const float* __restrict__ spart, bf16* __restrict__ attn_out)
{
    int idx = blockIdx.x * 256 + threadIdx.x;    // < B*S*D = 1048576
    int d = idx & 255;
    int h = d >> 5;
    int row = (idx >> 8) & (Sc - 1);
    int b = idx >> 19;
    float o = (__bfloat162float(op0[idx]) + __bfloat162float(op1[idx]))
            + (__bfloat162float(op2[idx]) + __bfloat162float(op3[idx]));
    float s = 0.f;
    #pragma unroll
    for (int r = 0; r < 4; ++r)
        s += spart[((size_t)(r * Bc + b) * Hc + h) * Sc + row];
    attn_out[idx] = __float2bfloat16(o / fmaxf(s, 1e-30f));
}

// xf = LN(a + xf)*g + b; xb = bf16(xf); optionally also write final output.
__global__ __launch_bounds__(256) void add_ln(
    const float* __restrict__ a, float* __restrict__ xf, bf16* __restrict__ xb,
    const float* __restrict__ g, const float* __restrict__ b,
    void* __restrict__ dout, const int* __restrict__ flags)
{
    __shared__ float ws4[2][4];
    int row = blockIdx.x, d = threadIdx.x;
    size_t idx = (size_t)row * Dc + d;
    float v = a[idx] + xf[idx];
    float s = v;
    #pragma unroll
    for (int dd = 1; dd < 64; dd <<= 1) s += __shfl_xor(s, dd);
    if ((d & 63) == 0) ws4[0][d >> 6] = s;
    __syncthreads();
    float mu = (ws4[0][0] + ws4[0][1] + ws4[0][2] + ws4[0][3]) * (1.f / Dc);
    float c = v - mu;
    float q = c * c;
    #pragma unroll
    for (int dd = 1; dd < 64; dd <<= 1) q += __shfl_xor(q, dd);
    if ((d & 63) == 0) ws4[1][d >> 6] = q;
    __syncthreads();
    float var = (ws4[1][0] + ws4[1][1] + ws4[1][2] + ws4[1][3]) * (1.f / Dc);
    float r2 = c * rsqrtf(var + 1e-7f) * g[d] + b[d];
    xf[idx] = r2;
    xb[idx] = __float2bfloat16(r2);
    if (dout) {
        if (flags[0]) ((bf16*)dout)[idx] = __float2bfloat16(r2);
        else          ((float*)dout)[idx] = r2;
    }
}

// ---------------------------------------------------------------------------
extern "C" void kernel_launch(void* const* d_in, const int* in_sizes, int n_in,
                              void* d_out, int out_size, void* d_ws, size_t ws_size,
                              hipStream_t stream)
{
    const void* x    = d_in[0];
    const void* mask = d_in[1];
    const void* pe   = d_in[2];
    const void* Wq   = d_in[3];
    const void* Wk   = d_in[4];
    const void* Wv   = d_in[5];
    const void* Wo   = d_in[6];
    const void* bo   = d_in[7];
    const void* ln1g = d_in[8];
    const void* ln1b = d_in[9];
    const void* W1   = d_in[10];
    const void* b1   = d_in[11];
    const void* W2   = d_in[12];
    const void* b2   = d_in[13];
    const void* ln2g = d_in[14];
    const void* ln2b = d_in[15];

    const int M = Bc * Sc;  // 4096
    char* ws = (char*)d_ws;
    const size_t MB = 1024 * 1024;
    int*      flags    = (int*)ws;                        // 256 B
    float*    xf32     = (float*)(ws + 256);              // 4 MiB
    float*    obuf     = (float*)(ws + 256 + 4 * MB);     // 4 MiB (op0/op1)
    char*     bigc     = ws + 256 + 8 * MB;               // 8 MiB (qkv/hbuf/op3)
    bf16*     xbf      = (bf16*)(ws + 256 + 16 * MB);     // 2 MiB
    bf16*     attn_out = (bf16*)(ws + 256 + 18 * MB);     // 2 MiB (op2 alias)
    bf16*     wqkv     = (bf16*)(ws + 256 + 20 * MB);     // weights (BT)
    bf16*     woc      = wqkv + (size_t)Lc * Dc * 3 * Dc;
    bf16*     w1c      = woc + (size_t)Lc * Dc * Dc;
    bf16*     w2c      = w1c + (size_t)Lc * Dc * Fc;
    float*    pc       = (float*)(w2c + (size_t)Lc * Fc * Dc);
    unsigned* pmask    = (unsigned*)(ws + 256 + 25 * MB); // 1 MiB
    float*    spart    = (float*)(ws + 256 + 26 * MB);    // 512 KiB (4 ranges)

    bf16* qkv  = (bf16*)bigc;          // M*768 bf16 = exactly 6 MiB
    bf16* hbuf = (bf16*)bigc;          // M*1024 bf16 = 8 MiB (qkv+op3 dead)
    bf16* op0  = (bf16*)obuf;          // 2 MiB
    bf16* op1  = op0 + (size_t)M * Dc; // 2 MiB
    bf16* op2  = attn_out;             // 2 MiB (merge writes same idx after read)
    bf16* op3  = (bf16*)(bigc + 6 * MB); // 2 MiB tail of bigc (free during flash)

    float* pc_bo   = pc;
    float* pc_b1   = pc + 768;
    float* pc_b2   = pc + 3840;
    float* pc_ln1g = pc + 4608;
    float* pc_ln1b = pc + 5376;
    float* pc_ln2g = pc + 6144;
    float* pc_ln2b = pc + 6912;

    prologue_fused<<<NBLK_REPACK + NBLK_CONV + NBLK_PACK + NBLK_PE, 256, 0, stream>>>(
        x, mask, pe, Wq, Wk, Wv, Wo, W1, W2, bo, b1, b2,
        ln1g, ln1b, ln2g, ln2b, wqkv, woc, pc, pmask, xf32, xbf, flags);

    for (int l = 0; l < Lc; ++l) {
        // QKV: [4096,256] @ BT[768,256] -> bf16; q cols pre-scaled by QSCALE
        gemm_mfma<<<dim3(3 * Dc / 64, M / 64), 256, 0, stream>>>(
            xbf, wqkv + (size_t)l * Dc * 3 * Dc, nullptr, qkv, M, 3 * Dc, Dc, 0, 1,
            QSCALE, Dc);
        flash_mfma<<<dim3(Sc / 64, Hc, Bc * 4), 256, 0, stream>>>(
            qkv, pmask, op0, op1, op2, op3, spart);
        attn_merge<<<(Bc * Sc * Dc) / 256, 256, 0, stream>>>(
            op0, op1, op2, op3, spart, attn_out);
        // Wo: [4096,256] @ BT[256,256] + bo -> f32 (32-row tile, 2 blocks/CU)
        gemm_mfma32<<<dim3(Dc / 64, M / 32), 256, 0, stream>>>(
            attn_out, woc + (size_t)l * Dc * Dc, pc_bo + l * Dc, obuf, M, Dc, Dc, 0, 0);
        add_ln<<<M, 256, 0, stream>>>(obuf, xf32, xbf,
            pc_ln1g + l * Dc, pc_ln1b + l * Dc, nullptr, flags);
        // FFN1: [4096,256] @ BT[1024,256] + b1, relu -> bf16
        gemm_mfma<<<dim3(Fc / 64, M / 64), 256, 0, stream>>>(
            xbf, w1c + (size_t)l * Dc * Fc, pc_b1 + l * Fc, hbuf, M, Fc, Dc, 1, 1,
            1.f, 0);
        // FFN2: [4096,1024] @ BT[256,1024] + b2 -> f32 (32-row tile)
        gemm_mfma32<<<dim3(Dc / 64, M / 32), 256, 0, stream>>>(
            hbuf, w2c + (size_t)l * Fc * Dc, pc_b2 + l * Dc, obuf, M, Dc, Fc, 0, 0);
        // last LN also writes the final output (store_out folded in)
        add_ln<<<M, 256, 0, stream>>>(obuf, xf32, xbf,
            pc_ln2g + l * Dc, pc_ln2b + l * Dc,
            (l == Lc - 1) ? d_out : nullptr, flags);
    }
}

// Round 17
// 381.915 us; speedup vs baseline: 1.0614x; 1.0028x over previous
//
#include <hip/hip_runtime.h>
#include <hip/hip_bf16.h>
#include <cfloat>

// Problem: L=3, B=2, S=2048, D=256, H=8, DK=32, F=1024
#define Lc 3
#define Bc 2
#define Sc 2048
#define Dc 256
#define Hc 8
#define DKc 32
#define Fc 1024

typedef __hip_bfloat16 bf16;
typedef short s8v __attribute__((ext_vector_type(8)));
typedef float f4v __attribute__((ext_vector_type(4)));

// 1/sqrt(32) * log2(e): folded into Q at the QKV-GEMM epilogue so flash can
// use exp2 directly with no per-element scale.
#define QSCALE 0.25504526036067815f

__device__ __forceinline__ float load_f(const void* p, size_t i, int isbf)
{
    return isbf ? __bfloat162float(((const bf16*)p)[i]) : ((const float*)p)[i];
}

// async global->LDS, 16B per lane; LDS dest = wave-uniform base + lane*16.
typedef const __attribute__((address_space(1))) char gchar_t;
typedef __attribute__((address_space(3))) char lchar_t;
__device__ __forceinline__ void glds16(const void* g, void* l)
{
    __builtin_amdgcn_global_load_lds((gchar_t*)(size_t)g, (lchar_t*)(size_t)l,
                                     16, 0, 0);
}

// ---------------------------------------------------------------------------
// Fused prologue (unchanged). Weights written TRANSPOSED (BT layout [N][K]).
// ---------------------------------------------------------------------------
#define NBLK_REPACK 2304
#define NBLK_CONV   6942
#define NBLK_PACK   1024
#define NBLK_PE     4096

__global__ __launch_bounds__(256) void prologue_fused(
    const void* __restrict__ x, const void* __restrict__ mask,
    const void* __restrict__ pe,
    const void* Wq, const void* Wk, const void* Wv,
    const void* Wo, const void* W1, const void* W2,
    const void* bo, const void* b1, const void* b2,
    const void* g1, const void* be1, const void* g2, const void* be2,
    bf16* __restrict__ wqkv, bf16* __restrict__ dstb, float* __restrict__ pc,
    unsigned* __restrict__ pmask, float* __restrict__ xf,
    bf16* __restrict__ xb, int* __restrict__ flags)
{
    __shared__ int sf[2];
    int tid = threadIdx.x;
    if (tid < 64) {
        const unsigned short* u16 = (const unsigned short*)x;
        int cnt = 0;
        for (int i = tid; i < 256; i += 64) {
            unsigned e = (u16[2 * i] >> 7) & 0xFF;
            cnt += (e >= 90 && e <= 140) ? 1 : 0;
        }
        #pragma unroll
        for (int d = 1; d < 64; d <<= 1) cnt += __shfl_xor(cnt, d);
        const unsigned* mu = (const unsigned*)mask;
        int c2 = ((mu[tid] & 0xFFFFFF00u) == 0) ? 1 : 0;
        #pragma unroll
        for (int d = 1; d < 64; d <<= 1) c2 += __shfl_xor(c2, d);
        if (tid == 0) {
            sf[0] = (cnt >= 128) ? 1 : 0;
            sf[1] = (c2 >= 48) ? 1 : 0;
            if (blockIdx.x == 0) { flags[0] = sf[0]; flags[1] = sf[1]; }
        }
    }
    __syncthreads();
    int isbf = sf[0], mf = sf[1];
    int blk = blockIdx.x;

    if (blk < NBLK_REPACK) {
        int idx = blk * 256 + tid;
        int l   = idx / (3 * Dc * Dc);
        int rem = idx % (3 * Dc * Dc);
        int col = rem / Dc;          // 0..767
        int d   = rem % Dc;
        int mat = col / Dc;
        int hk  = col % Dc;
        int h = hk / DKc, kk = hk % DKc;
        const void* W = (mat == 0) ? Wq : (mat == 1) ? Wk : Wv;
        float v = load_f(W, (size_t)l * (Hc * Dc * DKc) + h * (Dc * DKc) + d * DKc + kk, isbf);
        wqkv[idx] = __float2bfloat16(v);
    } else if (blk < NBLK_REPACK + NBLK_CONV) {
        const int NB0 = Lc * Dc * Dc;            // 196608
        const int NB1 = NB0 + Lc * Dc * Fc;      // 983040
        const int NB2 = NB1 + Lc * Fc * Dc;      // 1769472
        int idx = (blk - NBLK_REPACK) * 256 + tid;
        if (idx < NB2) {
            const void* src; int off;
            if (idx < NB0) {
                int l = idx / (Dc * Dc); int rem = idx % (Dc * Dc);
                int n = rem / Dc, k = rem % Dc;
                src = Wo; off = l * Dc * Dc + k * Dc + n;
            } else if (idx < NB1) {
                int j = idx - NB0;
                int l = j / (Fc * Dc); int rem = j % (Fc * Dc);
                int n = rem / Dc, k = rem % Dc;
                src = W1; off = l * Dc * Fc + k * Fc + n;
            } else {
                int j = idx - NB1;
                int l = j / (Dc * Fc); int rem = j % (Dc * Fc);
                int n = rem / Fc, k = rem % Fc;
                src = W2; off = l * Fc * Dc + k * Dc + n;
            }
            dstb[idx] = __float2bfloat16(load_f(src, off, isbf));
        } else {
            int off = idx - NB2;
            if (off < 7680) {
                const void* src; int lo;
                if (off < 768)       { src = bo;  lo = off; }
                else if (off < 3840) { src = b1;  lo = off - 768; }
                else if (off < 4608) { src = b2;  lo = off - 3840; }
                else if (off < 5376) { src = g1;  lo = off - 4608; }
                else if (off < 6144) { src = be1; lo = off - 5376; }
                else if (off < 6912) { src = g2;  lo = off - 6144; }
                else                 { src = be2; lo = off - 6912; }
                pc[off] = load_f(src, lo, isbf);
            }
        }
    } else if (blk < NBLK_REPACK + NBLK_CONV + NBLK_PACK) {
        int idx = (blk - NBLK_REPACK - NBLK_CONV) * 256 + tid;  // < B*S*S/32
        unsigned wb = 0;
        if (mf) {
            const int* mp = (const int*)mask + (size_t)idx * 32;
            #pragma unroll
            for (int u = 0; u < 8; ++u) {
                uint4 q = *(const uint4*)(mp + u * 4);
                wb |= (q.x ? 1u : 0u) << (u * 4);
                wb |= (q.y ? 1u : 0u) << (u * 4 + 1);
                wb |= (q.z ? 1u : 0u) << (u * 4 + 2);
                wb |= (q.w ? 1u : 0u) << (u * 4 + 3);
            }
        } else {
            const unsigned char* mp = (const unsigned char*)mask + (size_t)idx * 32;
            uint4 a = *(const uint4*)mp;
            uint4 bq = *(const uint4*)(mp + 16);
            const unsigned char* ab = (const unsigned char*)&a;
            const unsigned char* bb = (const unsigned char*)&bq;
            #pragma unroll
            for (int j = 0; j < 16; ++j) {
                wb |= (ab[j] ? 1u : 0u) << j;
                wb |= (bb[j] ? 1u : 0u) << (16 + j);
            }
        }
        pmask[idx] = wb;
    } else {
        int idx = (blk - NBLK_REPACK - NBLK_CONV - NBLK_PACK) * 256 + tid;
        int rem = idx % (Sc * Dc);
        float v = load_f(x, idx, isbf) + load_f(pe, rem, isbf);
        xf[idx] = v;
        xb[idx] = __float2bfloat16(v);
    }
}

// ---------------------------------------------------------------------------
// MFMA GEMM v2: 64x64 tile, BT weights + global_load_lds, XOR-swizzled slots.
// Used for QKV (N=768) and FFN1 (N=1024).
// ---------------------------------------------------------------------------
__global__ __launch_bounds__(256) void gemm_mfma(
    const bf16* __restrict__ A, const bf16* __restrict__ BT,
    const float* __restrict__ bias, void* __restrict__ C,
    int M, int N, int K, int relu, int obf, float ascale, int scale_ncols)
{
    __shared__ __align__(16) short As[4096];
    __shared__ __align__(16) short Bs[4096];
    int tid = threadIdx.x;
    int w = tid >> 6, lane = tid & 63;
    int quad = lane >> 4, l15 = lane & 15;
    int wm0 = (w & 1) * 32, wn0 = (w >> 1) * 32;
    int row0 = blockIdx.y * 64, col0 = blockIdx.x * 64;

    int s0 = w * 128 + lane;
    int s1 = s0 + 64;
    int r0 = s0 >> 3, c0 = ((s0 & 7) ^ (r0 & 7)) * 8;
    int r1 = s1 >> 3, c1 = ((s1 & 7) ^ (r1 & 7)) * 8;
    const bf16* Ag0 = A + (size_t)(row0 + r0) * K + c0;
    const bf16* Ag1 = A + (size_t)(row0 + r1) * K + c1;
    const bf16* Bg0 = BT + (size_t)(col0 + r0) * K + c0;
    const bf16* Bg1 = BT + (size_t)(col0 + r1) * K + c1;
    short* Ad0 = As + w * 1024;
    short* Ad1 = As + w * 1024 + 512;
    short* Bd0 = Bs + w * 1024;
    short* Bd1 = Bs + w * 1024 + 512;

    f4v acc00 = {0.f,0.f,0.f,0.f}, acc01 = acc00, acc10 = acc00, acc11 = acc00;

    int m0 = wm0 + l15, m1 = wm0 + 16 + l15;
    int n0 = wn0 + l15, n1 = wn0 + 16 + l15;
    int sw7 = l15 & 7;

    for (int k0 = 0; k0 < K; k0 += 64) {
        glds16(Ag0 + k0, Ad0);
        glds16(Ag1 + k0, Ad1);
        glds16(Bg0 + k0, Bd0);
        glds16(Bg1 + k0, Bd1);
        __syncthreads();
        #pragma unroll
        for (int kc = 0; kc < 2; ++kc) {
            int sw = ((kc * 4 + quad) ^ sw7) * 8;
            s8v a0 = *(const s8v*)(As + m0 * 64 + sw);
            s8v a1 = *(const s8v*)(As + m1 * 64 + sw);
            s8v b0 = *(const s8v*)(Bs + n0 * 64 + sw);
            s8v b1 = *(const s8v*)(Bs + n1 * 64 + sw);
            acc00 = __builtin_amdgcn_mfma_f32_16x16x32_bf16(a0, b0, acc00, 0, 0, 0);
            acc01 = __builtin_amdgcn_mfma_f32_16x16x32_bf16(a0, b1, acc01, 0, 0, 0);
            acc10 = __builtin_amdgcn_mfma_f32_16x16x32_bf16(a1, b0, acc10, 0, 0, 0);
            acc11 = __builtin_amdgcn_mfma_f32_16x16x32_bf16(a1, b1, acc11, 0, 0, 0);
        }
        __syncthreads();
    }

    float bv0 = bias ? bias[col0 + wn0 + l15] : 0.f;
    float bv1 = bias ? bias[col0 + wn0 + 16 + l15] : 0.f;
    f4v accs[2][2] = {{acc00, acc01}, {acc10, acc11}};
    #pragma unroll
    for (int mt = 0; mt < 2; ++mt) {
        #pragma unroll
        for (int nt = 0; nt < 2; ++nt) {
            int gr = row0 + wm0 + mt * 16 + quad * 4;
            int gc = col0 + wn0 + nt * 16 + l15;
            float badd = nt ? bv1 : bv0;
            float sc = (gc < scale_ncols) ? ascale : 1.f;
            #pragma unroll
            for (int reg = 0; reg < 4; ++reg) {
                float v = accs[mt][nt][reg] * sc + badd;
                if (relu) v = fmaxf(v, 0.f);
                if (obf) ((bf16*)C)[(size_t)(gr + reg) * N + gc] = __float2bfloat16(v);
                else     ((float*)C)[(size_t)(gr + reg) * N + gc] = v;
            }
        }
    }
}

// ---------------------------------------------------------------------------
// MFMA GEMM v3: 32x64 tile for the N=256 GEMMs (Wo, FFN2).
// ---------------------------------------------------------------------------
__global__ __launch_bounds__(256) void gemm_mfma32(
    const bf16* __restrict__ A, const bf16* __restrict__ BT,
    const float* __restrict__ bias, void* __restrict__ C,
    int M, int N, int K, int relu, int obf)
{
    __shared__ __align__(16) short As[2048];
    __shared__ __align__(16) short Bs[4096];
    int tid = threadIdx.x;
    int w = tid >> 6, lane = tid & 63;
    int quad = lane >> 4, l15 = lane & 15;
    int wm0 = (w & 1) * 16, wn0 = (w >> 1) * 32;
    int row0 = blockIdx.y * 32, col0 = blockIdx.x * 64;

    int sa = w * 64 + lane;                    // A slot 0..255
    int ra = sa >> 3, ca = ((sa & 7) ^ (ra & 7)) * 8;
    int s0 = w * 128 + lane, s1 = s0 + 64;     // B slots 0..511
    int r0 = s0 >> 3, c0 = ((s0 & 7) ^ (r0 & 7)) * 8;
    int r1 = s1 >> 3, c1 = ((s1 & 7) ^ (r1 & 7)) * 8;
    const bf16* Ag  = A + (size_t)(row0 + ra) * K + ca;
    const bf16* Bg0 = BT + (size_t)(col0 + r0) * K + c0;
    const bf16* Bg1 = BT + (size_t)(col0 + r1) * K + c1;
    short* Ad  = As + w * 512;
    short* Bd0 = Bs + w * 1024;
    short* Bd1 = Bs + w * 1024 + 512;

    f4v acc0 = {0.f,0.f,0.f,0.f}, acc1 = acc0;

    int m0 = wm0 + l15;
    int n0 = wn0 + l15, n1 = wn0 + 16 + l15;
    int sw7 = l15 & 7;

    for (int k0 = 0; k0 < K; k0 += 64) {
        glds16(Ag + k0, Ad);
        glds16(Bg0 + k0, Bd0);
        glds16(Bg1 + k0, Bd1);
        __syncthreads();
        #pragma unroll
        for (int kc = 0; kc < 2; ++kc) {
            int sw = ((kc * 4 + quad) ^ sw7) * 8;
            s8v a0 = *(const s8v*)(As + m0 * 64 + sw);
            s8v b0 = *(const s8v*)(Bs + n0 * 64 + sw);
            s8v b1 = *(const s8v*)(Bs + n1 * 64 + sw);
            acc0 = __builtin_amdgcn_mfma_f32_16x16x32_bf16(a0, b0, acc0, 0, 0, 0);
            acc1 = __builtin_amdgcn_mfma_f32_16x16x32_bf16(a0, b1, acc1, 0, 0, 0);
        }
        __syncthreads();
    }

    float bv0 = bias ? bias[col0 + wn0 + l15] : 0.f;
    float bv1 = bias ? bias[col0 + wn0 + 16 + l15] : 0.f;
    f4v accs[2] = {acc0, acc1};
    #pragma unroll
    for (int nt = 0; nt < 2; ++nt) {
        int gr = row0 + wm0 + quad * 4;
        int gc = col0 + wn0 + nt * 16 + l15;
        float badd = nt ? bv1 : bv0;
        #pragma unroll
        for (int reg = 0; reg < 4; ++reg) {
            float v = accs[nt][reg] + badd;
            if (relu) v = fmaxf(v, 0.f);
            if (obf) ((bf16*)C)[(size_t)(gr + reg) * N + gc] = __float2bfloat16(v);
            else     ((float*)C)[(size_t)(gr + reg) * N + gc] = v;
        }
    }
}

// ---------------------------------------------------------------------------
// MFMA flash attention v8 = v6 + packed bf16 P-conversion
// (v_cvt_pk_bf16_f32 via __float22bfloat162_rn: 6 VALU slots -> 2 per
// reg-row; ~9% of the softmax VALU budget). 4-way t-split; NO-MAX softmax.
// ---------------------------------------------------------------------------
__global__ __launch_bounds__(256) void flash_mfma(
    const bf16* __restrict__ qkv, const unsigned* __restrict__ pmask,
    bf16* __restrict__ op0, bf16* __restrict__ op1,
    bf16* __restrict__ op2, bf16* __restrict__ op3,
    float* __restrict__ spart)
{
    __shared__ __align__(16) short Ks[64 * 40];   // K [t][dk]
    __shared__ __align__(16) short Vt[2336];      // V^T [d][sigma(t)] skewed
    __shared__ __align__(16) short Pw[4][16 * 72];

    int tid = threadIdx.x;
    int w = tid >> 6;
    int lane = tid & 63;
    int quad = lane >> 4, l15 = lane & 15;
    int q0 = blockIdx.x * 64;
    int h = blockIdx.y;
    int z = blockIdx.z;
    int b = z >> 2, rng = z & 3;
    bf16* op = (rng == 0) ? op0 : (rng == 1) ? op1 : (rng == 2) ? op2 : op3;

    s8v qfrag = *(const s8v*)(qkv + (size_t)(b * Sc + q0 + w * 16 + l15) * 768 + h * 32 + quad * 8);

    f4v o0 = {0.f,0.f,0.f,0.f}, o1 = o0;
    float ssum[4] = {0.f, 0.f, 0.f, 0.f};

    int st = tid >> 2, sd = (tid & 3) * 8;
    int sig = ((st & 15) << 2) | (st >> 4);          // sigma(st)
    short* pwv = Pw[w];
    const unsigned* pmrow = pmask + (size_t)b * Sc * (Sc / 32);

    for (int it = 0; it < 8; ++it) {
        int t0 = rng * (Sc / 4) + it * 64;
        __syncthreads();
        {
            const bf16* kvb = qkv + (size_t)(b * Sc + t0 + st) * 768 + h * 32 + sd;
            uint4 kw = *(const uint4*)(kvb + 256);
            *(uint4*)(Ks + st * 40 + sd) = kw;
            uint4 vw = *(const uint4*)(kvb + 512);
            const unsigned short* vu = (const unsigned short*)&vw;
            #pragma unroll
            for (int j = 0; j < 8; ++j) Vt[(sd + j) * 72 + sig + sd] = (short)vu[j];
        }
        unsigned mw0[4], mw1[4];
        #pragma unroll
        for (int reg = 0; reg < 4; ++reg) {
            int row = q0 + w * 16 + quad * 4 + reg;
            const unsigned* pp = pmrow + (size_t)row * (Sc / 32) + (t0 >> 5);
            mw0[reg] = pp[0];
            mw1[reg] = pp[1];
        }
        __syncthreads();

        f4v sfr[4];
        #pragma unroll
        for (int nt = 0; nt < 4; ++nt) {
            s8v kf = *(const s8v*)(Ks + (l15 + 16 * nt) * 40 + quad * 8);
            f4v zz = {0.f,0.f,0.f,0.f};
            sfr[nt] = __builtin_amdgcn_mfma_f32_16x16x32_bf16(qfrag, kf, zz, 0, 0, 0);
        }
        #pragma unroll
        for (int reg = 0; reg < 4; ++reg) {
            unsigned ta = mw0[reg] >> l15;
            unsigned tb = mw1[reg] >> l15;
            float p0 = exp2f(sfr[0][reg]); if (ta & 1u)         p0 = 0.f;
            float p1 = exp2f(sfr[1][reg]); if ((ta >> 16) & 1u) p1 = 0.f;
            float p2 = exp2f(sfr[2][reg]); if (tb & 1u)         p2 = 0.f;
            float p3 = exp2f(sfr[3][reg]); if ((tb >> 16) & 1u) p3 = 0.f;
            ssum[reg] += (p0 + p1) + (p2 + p3);
            __hip_bfloat162 plo = __float22bfloat162_rn(make_float2(p0, p1));
            __hip_bfloat162 phi = __float22bfloat162_rn(make_float2(p2, p3));
            uint2 pk = {*(unsigned*)&plo, *(unsigned*)&phi};
            *(uint2*)(pwv + (quad * 4 + reg) * 72 + l15 * 4) = pk;
        }
        #pragma unroll
        for (int kc = 0; kc < 2; ++kc) {
            s8v pf  = *(const s8v*)(pwv + l15 * 72 + kc * 32 + quad * 8);
            s8v vf0 = *(const s8v*)(Vt + l15 * 72 + kc * 32 + quad * 8 + (l15 & 24));
            s8v vf1 = *(const s8v*)(Vt + (l15 + 16) * 72 + kc * 32 + quad * 8 + ((l15 + 16) & 24));
            o0 = __builtin_amdgcn_mfma_f32_16x16x32_bf16(pf, vf0, o0, 0, 0, 0);
            o1 = __builtin_amdgcn_mfma_f32_16x16x32_bf16(pf, vf1, o1, 0, 0, 0);
        }
    }

    #pragma unroll
    for (int reg = 0; reg < 4; ++reg) {
        #pragma unroll
        for (int d = 1; d < 16; d <<= 1) ssum[reg] += __shfl_xor(ssum[reg], d);
    }

    #pragma unroll
    for (int reg = 0; reg < 4; ++reg) {
        int row = q0 + w * 16 + quad * 4 + reg;
        size_t ob = (size_t)(b * Sc + row) * Dc + h * DKc;
        op[ob + l15]      = __float2bfloat16(o0[reg]);
        op[ob + 16 + l15] = __float2bfloat16(o1[reg]);
        if (l15 == 0)
            spart[((size_t)(rng * Bc + b) * Hc + h) * Sc + row] = ssum[reg];
    }
}

// attn = sum_r o_r / sum_r s_r — vectorized: 8 bf16 per thread (uint4),
// one spart set per thread (an 8-chunk never straddles a head boundary).
__global__ __launch_bounds__(256) void attn_merge(
    const bf16* __restrict__ op0, const bf16* __restrict__ op1,
    const bf16* __restrict__ op2, const bf16* __restrict__ op3,
    const float* __restrict__ spart, bf16* __restrict__ attn_out)
{
    int t8 = blockIdx.x * 256 + threadIdx.x;     // < B*S*D/8 = 131072
    size_t idx = (size_t)t8 * 8;
    int d = (int)(idx & 255);
    int h = d >> 5;
    int row = (int)((idx >> 8) & (Sc - 1));
    int b = (int)(idx >> 19);
    float s = 0.f;
    #pragma unroll
    for (int r = 0; r < 4; ++r)
        s += spart[((size_t)(r * Bc + b) * Hc + h) * Sc + row];
    float inv = 1.f / fmaxf(s, 1e-30f);

    uint4 a0 = *(const uint4*)(op0 + idx);
    uint4 a1 = *(const uint4*)(op1 + idx);
    uint4 a2 = *(const uint4*)(op2 + idx);
    uint4 a3 = *(const uint4*)(op3 + idx);
    const unsigned short* u0 = (const unsigned short*)&a0;
    const unsigned short* u1 = (const unsigned short*)&a1;
    const unsigned short* u2 = (const unsigned short*)&a2;
    const unsigned short* u3 = (const unsigned short*)&a3;
    unsigned short outv[8];
    #pragma unroll
    for (int j = 0; j < 8; ++j) {
        float o = (__uint_as_float((unsigned)u0[j] << 16) + __uint_as_float((unsigned)u1[j] << 16))
                + (__uint_as_float((unsigned)u2[j] << 16) + __uint_as_float((unsigned)u3[j] << 16));
        bf16 ov = __float2bfloat16(o * inv);
        outv[j] = *(unsigned short*)&ov;
    }
    *(uint4*)(attn_out + idx) = *(uint4*)outv;
}

// xf = LN(a + xf)*g + b; xb = bf16(xf); optionally also write final output.
__global__ __launch_bounds__(256) void add_ln(
    const float* __restrict__ a, float* __restrict__ xf, bf16* __restrict__ xb,
    const float* __restrict__ g, const float* __restrict__ b,
    void* __restrict__ dout, const int* __restrict__ flags)
{
    __shared__ float ws4[2][4];
    int row = blockIdx.x, d = threadIdx.x;
    size_t idx = (size_t)row * Dc + d;
    float v = a[idx] + xf[idx];
    float s = v;
    #pragma unroll
    for (int dd = 1; dd < 64; dd <<= 1) s += __shfl_xor(s, dd);
    if ((d & 63) == 0) ws4[0][d >> 6] = s;
    __syncthreads();
    float mu = (ws4[0][0] + ws4[0][1] + ws4[0][2] + ws4[0][3]) * (1.f / Dc);
    float c = v - mu;
    float q = c * c;
    #pragma unroll
    for (int dd = 1; dd < 64; dd <<= 1) q += __shfl_xor(q, dd);
    if ((d & 63) == 0) ws4[1][d >> 6] = q;
    __syncthreads();
    float var = (ws4[1][0] + ws4[1][1] + ws4[1][2] + ws4[1][3]) * (1.f / Dc);
    float r2 = c * rsqrtf(var + 1e-7f) * g[d] + b[d];
    xf[idx] = r2;
    xb[idx] = __float2bfloat16(r2);
    if (dout) {
        if (flags[0]) ((bf16*)dout)[idx] = __float2bfloat16(r2);
        else          ((float*)dout)[idx] = r2;
    }
}

// ---------------------------------------------------------------------------
extern "C" void kernel_launch(void* const* d_in, const int* in_sizes, int n_in,
                              void* d_out, int out_size, void* d_ws, size_t ws_size,
                              hipStream_t stream)
{
    const void* x    = d_in[0];
    const void* mask = d_in[1];
    const void* pe   = d_in[2];
    const void* Wq   = d_in[3];
    const void* Wk   = d_in[4];
    const void* Wv   = d_in[5];
    const void* Wo   = d_in[6];
    const void* bo   = d_in[7];
    const void* ln1g = d_in[8];
    const void* ln1b = d_in[9];
    const void* W1   = d_in[10];
    const void* b1   = d_in[11];
    const void* W2   = d_in[12];
    const void* b2   = d_in[13];
    const void* ln2g = d_in[14];
    const void* ln2b = d_in[15];

    const int M = Bc * Sc;  // 4096
    char* ws = (char*)d_ws;
    const size_t MB = 1024 * 1024;
    int*      flags    = (int*)ws;                        // 256 B
    float*    xf32     = (float*)(ws + 256);              // 4 MiB
    float*    obuf     = (float*)(ws + 256 + 4 * MB);     // 4 MiB (op0/op1)
    char*     bigc     = ws + 256 + 8 * MB;               // 8 MiB (qkv/hbuf/op3)
    bf16*     xbf      = (bf16*)(ws + 256 + 16 * MB);     // 2 MiB
    bf16*     attn_out = (bf16*)(ws + 256 + 18 * MB);     // 2 MiB (op2 alias)
    bf16*     wqkv     = (bf16*)(ws + 256 + 20 * MB);     // weights (BT)
    bf16*     woc      = wqkv + (size_t)Lc * Dc * 3 * Dc;
    bf16*     w1c      = woc + (size_t)Lc * Dc * Dc;
    bf16*     w2c      = w1c + (size_t)Lc * Dc * Fc;
    float*    pc       = (float*)(w2c + (size_t)Lc * Fc * Dc);
    unsigned* pmask    = (unsigned*)(ws + 256 + 25 * MB); // 1 MiB
    float*    spart    = (float*)(ws + 256 + 26 * MB);    // 512 KiB (4 ranges)

    bf16* qkv  = (bf16*)bigc;          // M*768 bf16 = exactly 6 MiB
    bf16* hbuf = (bf16*)bigc;          // M*1024 bf16 = 8 MiB (qkv+op3 dead)
    bf16* op0  = (bf16*)obuf;          // 2 MiB
    bf16* op1  = op0 + (size_t)M * Dc; // 2 MiB
    bf16* op2  = attn_out;             // 2 MiB (merge writes same idx after read)
    bf16* op3  = (bf16*)(bigc + 6 * MB); // 2 MiB tail of bigc (free during flash)

    float* pc_bo   = pc;
    float* pc_b1   = pc + 768;
    float* pc_b2   = pc + 3840;
    float* pc_ln1g = pc + 4608;
    float* pc_ln1b = pc + 5376;
    float* pc_ln2g = pc + 6144;
    float* pc_ln2b = pc + 6912;

    prologue_fused<<<NBLK_REPACK + NBLK_CONV + NBLK_PACK + NBLK_PE, 256, 0, stream>>>(
        x, mask, pe, Wq, Wk, Wv, Wo, W1, W2, bo, b1, b2,
        ln1g, ln1b, ln2g, ln2b, wqkv, woc, pc, pmask, xf32, xbf, flags);

    for (int l = 0; l < Lc; ++l) {
        // QKV: [4096,256] @ BT[768,256] -> bf16; q cols pre-scaled by QSCALE
        gemm_mfma<<<dim3(3 * Dc / 64, M / 64), 256, 0, stream>>>(
            xbf, wqkv + (size_t)l * Dc * 3 * Dc, nullptr, qkv, M, 3 * Dc, Dc, 0, 1,
            QSCALE, Dc);
        flash_mfma<<<dim3(Sc / 64, Hc, Bc * 4), 256, 0, stream>>>(
            qkv, pmask, op0, op1, op2, op3, spart);
        attn_merge<<<(Bc * Sc * Dc / 8) / 256, 256, 0, stream>>>(
            op0, op1, op2, op3, spart, attn_out);
        // Wo: [4096,256] @ BT[256,256] + bo -> f32 (32-row tile, 2 blocks/CU)
        gemm_mfma32<<<dim3(Dc / 64, M / 32), 256, 0, stream>>>(
            attn_out, woc + (size_t)l * Dc * Dc, pc_bo + l * Dc, obuf, M, Dc, Dc, 0, 0);
        add_ln<<<M, 256, 0, stream>>>(obuf, xf32, xbf,
            pc_ln1g + l * Dc, pc_ln1b + l * Dc, nullptr, flags);
        // FFN1: [4096,256] @ BT[1024,256] + b1, relu -> bf16
        gemm_mfma<<<dim3(Fc / 64, M / 64), 256, 0, stream>>>(
            xbf, w1c + (size_t)l * Dc * Fc, pc_b1 + l * Fc, hbuf, M, Fc, Dc, 1, 1,
            1.f, 0);
        // FFN2: [4096,1024] @ BT[256,1024] + b2 -> f32 (32-row tile)
        gemm_mfma32<<<dim3(Dc / 64, M / 32), 256, 0, stream>>>(
            hbuf, w2c + (size_t)l * Fc * Dc, pc_b2 + l * Dc, obuf, M, Dc, Fc, 0, 0);
        // last LN also writes the final output (store_out folded in)
        add_ln<<<M, 256, 0, stream>>>(obuf, xf32, xbf,
            pc_ln2g + l * Dc, pc_ln2b + l * Dc,
            (l == Lc - 1) ? d_out : nullptr, flags);
    }
}